// Round 1
// 581.294 us; speedup vs baseline: 1.0639x; 1.0639x over previous
//
#include <hip/hip_runtime.h>
#include <stdint.h>

// B=16, T=S=E=D=1024 Luong attention. Inputs/outputs FP32 (per reference);
// compute in bf16 MFMA with fp32 accumulate. Outputs concat (fp32):
// h_tilde (16M) | attn_weights (16M) | attn_energies (16M).
//
// R1 changes vs 604us baseline:
//  * 2-phase double-buffered K-loop (stage t+1 issued BEFORE compute t, single
//    __syncthreads per step whose vmcnt(0) drains the in-flight prefetch).
//    Old loop exposed full global->LDS latency every K-step (MfmaUtil 17%).
//  * XCD-chunked block swizzle: flat id %8 = XCD; remap so each XCD owns 128
//    consecutive logical blocks = 2 whole batches. Old mapping spread the 8
//    blocks sharing an A-panel across all 8 XCDs -> 8x panel refetch
//    (FETCH 266MB vs 64MB unique; 16*2MB*8 + 32MB = 288MB matches).
//  * enc fp32->bf16 conversion fused into transconv_k (enc read once).
//
// Scratch:
//   ws[  0: 32MB] hidden_bf
//   ws[ 32: 64MB] enc_bf -> (dead after K1) wc_bf
//   ws[ 64: 96MB] proj_bf
//   ws[ 96: 98MB] Wattn_bf
//   ws[ 98:102MB] Wout_bf
//   out_h[0:32MB]  (as ushort) encT_bf     -- dead before K5 writes out_h
//   out_h[32:64MB] (as ushort) weights_bf  -- dead before K5 writes out_h

typedef __bf16 bf16x8 __attribute__((ext_vector_type(8)));
typedef float  f32x4  __attribute__((ext_vector_type(4)));

enum { MODE_PROJ = 0, MODE_ENERGY = 1, MODE_WC = 2, MODE_OUT = 3 };

__device__ __forceinline__ ushort f2bf(float f) {
    uint32_t u = __builtin_bit_cast(uint32_t, f);
    u += 0x7fffu + ((u >> 16) & 1u);   // round-to-nearest-even
    return (ushort)(u >> 16);
}

#define GLB_PTR(p) ((const __attribute__((address_space(1))) void*)(p))
#define LDS_PTR(p) ((__attribute__((address_space(3))) void*)(p))

// Stage a 128x64 bf16 tile (row stride `ld` elems) into LDS.
// LDS layout: row*128B + (chunk ^ (row&7))*16B (XOR swizzle; fragment-side
// ds_read_b128 is then <=2-way bank aliased = free). global_load_lds dest is
// wave-uniform base + lane*16 (m104/m108): each call fills 1 KiB contiguous.
__device__ __forceinline__ void stage_tile(const ushort* __restrict__ g, int ld,
                                           ushort* lds, int wave, int lane) {
#pragma unroll
    for (int i = 0; i < 4; ++i) {
        const int seg  = i * 4 + wave;
        const int p    = seg * 1024 + lane * 16;
        const int row  = p >> 7;
        const int cpos = (p >> 4) & 7;
        const int csrc = cpos ^ (row & 7);
        const ushort* gp = g + (size_t)row * ld + csrc * 8;
        __builtin_amdgcn_global_load_lds(GLB_PTR(gp), LDS_PTR((char*)lds + seg * 1024), 16, 0, 0);
    }
}

// C(1024,1024) = A(1024,K) @ B(N,K)^T per batch. 128x128 tile/block, 4 waves
// 2x2, each wave 64x64 via 4x4 mfma_f32_16x16x32_bf16. BK=64, double-buffered.
template <int MODE>
__global__ __launch_bounds__(256) void gemm_bt(
    const ushort* __restrict__ A0, const ushort* __restrict__ A1,
    const ushort* __restrict__ B0, const float* __restrict__ bias,
    ushort* __restrict__ out_bf, float* __restrict__ out_f)
{
    constexpr int    KTOT   = (MODE == MODE_OUT) ? 2048 : 1024;
    constexpr int    LDB    = (MODE == MODE_OUT) ? 2048 : 1024;
    constexpr int    NT     = KTOT / 64;          // 16 or 32, even
    constexpr size_t BBATCH = (MODE == MODE_ENERGY || MODE == MODE_WC) ? ((size_t)1 << 20) : 0;

    // XCD-chunked swizzle: hw dispatch round-robins flat%8 across XCDs.
    // Remap so XCD k gets logical blocks [k*128, (k+1)*128) = batches 2k,2k+1.
    // Within a chunk, bn varies fastest -> A-panel stays hot in that L2.
    const int flat = (blockIdx.z * 8 + blockIdx.y) * 8 + blockIdx.x;
    const int nid  = ((flat & 7) << 7) | (flat >> 3);
    const int b    = nid >> 6;
    const int bm   = ((nid >> 3) & 7) << 7;
    const int bn   = (nid & 7) << 7;

    const int wave = threadIdx.x >> 6;
    const int lane = threadIdx.x & 63;
    const int wm   = wave >> 1;
    const int wn   = wave & 1;

    const ushort* Ab0 = A0 + ((size_t)b << 20) + (size_t)bm * 1024;
    const ushort* Ab1 = nullptr;
    if constexpr (MODE == MODE_OUT) Ab1 = A1 + ((size_t)b << 20) + (size_t)bm * 1024;
    const ushort* Bb0 = B0 + (size_t)b * BBATCH + (size_t)bn * LDB;

    __shared__ ushort ldsA[2][128 * 64];
    __shared__ ushort ldsB[2][128 * 64];

    f32x4 acc[4][4];
#pragma unroll
    for (int r = 0; r < 4; ++r)
#pragma unroll
        for (int c = 0; c < 4; ++c) acc[r][c] = f32x4{0.f, 0.f, 0.f, 0.f};

    auto stage_step = [&](int t, int buf) {
        const int k0 = t * 64;
        const ushort* Ag; int kA;
        if constexpr (MODE == MODE_OUT) { Ag = (k0 < 1024) ? Ab0 : Ab1; kA = k0 & 1023; }
        else                            { Ag = Ab0;                     kA = k0; }
        stage_tile(Ag + kA, 1024, ldsA[buf], wave, lane);
        stage_tile(Bb0 + k0, LDB,  ldsB[buf], wave, lane);
    };

    auto compute_step = [&](int buf) {
#pragma unroll
        for (int ks = 0; ks < 2; ++ks) {
            const int quad = lane >> 4;
            const int l15  = lane & 15;
            bf16x8 af[4], bfr[4];
#pragma unroll
            for (int r = 0; r < 4; ++r) {
                const int row   = wm * 64 + r * 16 + l15;
                const int chunk = ks * 4 + quad;
                af[r] = *(const bf16x8*)&ldsA[buf][row * 64 + ((chunk ^ (row & 7)) * 8)];
            }
#pragma unroll
            for (int c = 0; c < 4; ++c) {
                const int row   = wn * 64 + c * 16 + l15;
                const int chunk = ks * 4 + quad;
                bfr[c] = *(const bf16x8*)&ldsB[buf][row * 64 + ((chunk ^ (row & 7)) * 8)];
            }
#pragma unroll
            for (int r = 0; r < 4; ++r)
#pragma unroll
                for (int c = 0; c < 4; ++c)
                    acc[r][c] = __builtin_amdgcn_mfma_f32_16x16x32_bf16(af[r], bfr[c], acc[r][c], 0, 0, 0);
        }
    };

    // Prologue: stage tile 0 into buf0; __syncthreads drains vmcnt(0).
    stage_step(0, 0);
    __syncthreads();

    // 2-phase pipeline, manually unrolled x2 so LDS buffer indices are static.
    // Hazards: STAGE into buf X at iter t overwrites data last ds_read at iter
    // t-1; the end-of-(t-1) barrier (lgkmcnt(0)+vmcnt(0) before s_barrier)
    // happens-after those reads. Reads of buf[cur] at iter t see the stage
    // issued at iter t-1 because the same barrier drains vmcnt(0).
    for (int t = 0; t < NT; t += 2) {
        stage_step(t + 1, 1);          // prefetch odd tile (t+1 < NT: NT even)
        compute_step(0);
        __syncthreads();
        if (t + 2 < NT) stage_step(t + 2, 0);   // prefetch next even tile
        compute_step(1);
        __syncthreads();
    }

    // Epilogue. C/D layout (16x16x32, m89/m91): col=lane&15, row=(lane>>4)*4+reg.
    const size_t obase = (size_t)b << 20;
    const int quad = lane >> 4;
    const int l15  = lane & 15;
#pragma unroll
    for (int r = 0; r < 4; ++r) {
#pragma unroll
        for (int c = 0; c < 4; ++c) {
#pragma unroll
            for (int g = 0; g < 4; ++g) {
                const int row = bm + wm * 64 + r * 16 + quad * 4 + g;
                const int col = bn + wn * 64 + c * 16 + l15;
                float v = acc[r][c][g];
                const size_t idx = obase + (size_t)row * 1024 + col;
                if constexpr (MODE == MODE_PROJ) {
                    out_bf[idx] = f2bf(v + bias[col]);   // b_attn along d
                } else if constexpr (MODE == MODE_ENERGY) {
                    out_f[idx] = v;                      // fp32 energies (final)
                } else if constexpr (MODE == MODE_WC) {
                    out_bf[idx] = f2bf(v);
                } else {
                    out_f[idx] = tanhf(v);               // fp32 h_tilde (final)
                }
            }
        }
    }
}

// fp32 -> bf16 elementwise, 4 elems/thread, exact grid.
__global__ __launch_bounds__(256) void conv_k(const float* __restrict__ in,
                                              ushort* __restrict__ out) {
    const size_t i = (size_t)blockIdx.x * 256 + threadIdx.x;
    float4 v = ((const float4*)in)[i];
    ushort4 o;
    o.x = f2bf(v.x); o.y = f2bf(v.y); o.z = f2bf(v.z); o.w = f2bf(v.w);
    ((ushort4*)out)[i] = o;
}

// Fused: encT_bf[b,e,s] = bf16(enc[b,s,e]) AND encN_bf[b,s,e] = bf16(enc[b,s,e]).
// fp32 in, bf16 out, 64x64 tiles; enc is read exactly once.
__global__ __launch_bounds__(256) void transconv_k(const float* __restrict__ in,
                                                   ushort* __restrict__ outT,
                                                   ushort* __restrict__ outN) {
    __shared__ ushort t[64][65];
    const int b  = blockIdx.z;
    const int s0 = blockIdx.y * 64, e0 = blockIdx.x * 64;
    const float* ip = in   + ((size_t)b << 20);
    ushort*      tp = outT + ((size_t)b << 20);
    ushort*      np = outN + ((size_t)b << 20);
    const int tx = threadIdx.x & 15;   // 16 float4 groups = 64 cols
    const int ty = threadIdx.x >> 4;   // 16 rows per pass
#pragma unroll
    for (int i = 0; i < 4; ++i) {
        const int s = ty + i * 16;
        float4 v = *(const float4*)&ip[(size_t)(s0 + s) * 1024 + e0 + tx * 4];
        ushort4 n4;
        n4.x = f2bf(v.x); n4.y = f2bf(v.y); n4.z = f2bf(v.z); n4.w = f2bf(v.w);
        *(ushort4*)&np[(size_t)(s0 + s) * 1024 + e0 + tx * 4] = n4;
        t[tx * 4 + 0][s] = n4.x; t[tx * 4 + 1][s] = n4.y;
        t[tx * 4 + 2][s] = n4.z; t[tx * 4 + 3][s] = n4.w;
    }
    __syncthreads();
#pragma unroll
    for (int i = 0; i < 4; ++i) {
        const int e = ty + i * 16;
        ushort4 v;
        v.x = t[e][tx * 4 + 0]; v.y = t[e][tx * 4 + 1];
        v.z = t[e][tx * 4 + 2]; v.w = t[e][tx * 4 + 3];
        *(ushort4*)&tp[(size_t)(e0 + e) * 1024 + s0 + tx * 4] = v;
    }
}

// Row softmax over S=1024; fp32 in -> fp32 out (final) + bf16 out (for PV GEMM).
__global__ __launch_bounds__(256) void softmax_k(const float* __restrict__ en,
                                                 float* __restrict__ w,
                                                 ushort* __restrict__ wbf) {
    const size_t row = blockIdx.x;
    const float* e = en + (row << 10);
    const int tid = threadIdx.x;
    const int wv = tid >> 6, ln = tid & 63;

    float4 v = ((const float4*)e)[tid];
    float m = fmaxf(fmaxf(v.x, v.y), fmaxf(v.z, v.w));
#pragma unroll
    for (int o = 32; o; o >>= 1) m = fmaxf(m, __shfl_xor(m, o, 64));
    __shared__ float sm[4];
    if (!ln) sm[wv] = m;
    __syncthreads();
    m = fmaxf(fmaxf(sm[0], sm[1]), fmaxf(sm[2], sm[3]));

    const float e0 = expf(v.x - m), e1 = expf(v.y - m), e2 = expf(v.z - m), e3 = expf(v.w - m);
    float s = e0 + e1 + e2 + e3;
#pragma unroll
    for (int o = 32; o; o >>= 1) s += __shfl_xor(s, o, 64);
    __shared__ float ss[4];
    if (!ln) ss[wv] = s;
    __syncthreads();
    s = ss[0] + ss[1] + ss[2] + ss[3];
    const float inv = 1.0f / s;

    const float w0 = e0 * inv, w1 = e1 * inv, w2 = e2 * inv, w3 = e3 * inv;
    ((float4*)(w + (row << 10)))[tid] = float4{w0, w1, w2, w3};
    ushort4 o4;
    o4.x = f2bf(w0); o4.y = f2bf(w1); o4.z = f2bf(w2); o4.w = f2bf(w3);
    ((ushort4*)(wbf + (row << 10)))[tid] = o4;
}

extern "C" void kernel_launch(void* const* d_in, const int* in_sizes, int n_in,
                              void* d_out, int out_size, void* d_ws, size_t ws_size,
                              hipStream_t stream) {
    (void)in_sizes; (void)n_in; (void)out_size; (void)ws_size;
    const float* hidden = (const float*)d_in[0];  // (16,1024,1024) fp32
    const float* enc    = (const float*)d_in[1];  // (16,1024,1024) fp32
    const float* Wattn  = (const float*)d_in[2];  // (1024,1024)    fp32
    const float* battn  = (const float*)d_in[3];  // (1024,)        fp32
    const float* Wout   = (const float*)d_in[4];  // (1024,2048)    fp32

    const size_t M16 = (size_t)16 * 1024 * 1024;
    float* out_h = (float*)d_out;     // h_tilde (final); scratch before K5
    float* out_w = out_h + M16;       // attn_weights (final)
    float* out_e = out_w + M16;       // attn_energies (final)

    ushort* ws = (ushort*)d_ws;
    ushort* hidden_bf = ws;                 // 16M elems
    ushort* encwc_bf  = ws + M16;           // enc_bf, then wc_bf
    ushort* proj_bf   = ws + 2 * M16;
    ushort* wattn_bf  = ws + 3 * M16;       // 1M elems
    ushort* wout_bf   = ws + 3 * M16 + (1u << 20);  // 2M elems
    ushort* encT_bf   = (ushort*)out_h;                 // 16M elems (32 MB)
    ushort* weights_bf = (ushort*)out_h + M16;          // 16M elems (32 MB)

    dim3 blk(256, 1, 1);
    dim3 gG(8, 8, 16);     // GEMMs: 128x128 tiles
    dim3 gT(16, 16, 16);   // transpose-conv: 64x64 tiles

    // K0: fp32 -> bf16 conversions (enc handled inside transconv_k, read once)
    conv_k<<<dim3(16384), blk, 0, stream>>>(hidden, hidden_bf);
    conv_k<<<dim3(1024),  blk, 0, stream>>>(Wattn, wattn_bf);
    conv_k<<<dim3(2048),  blk, 0, stream>>>(Wout, wout_bf);
    transconv_k<<<gT, blk, 0, stream>>>(enc, encT_bf, encwc_bf);
    // K1: proj = enc @ W_attn^T + b_attn -> bf16 (ws)
    gemm_bt<MODE_PROJ><<<gG, blk, 0, stream>>>(encwc_bf, nullptr, wattn_bf, battn,
                                               proj_bf, nullptr);
    // K2: energies = hidden @ proj^T -> fp32 out_e (final)
    gemm_bt<MODE_ENERGY><<<gG, blk, 0, stream>>>(hidden_bf, nullptr, proj_bf, nullptr,
                                                 nullptr, out_e);
    // K3: weights = softmax(energies) -> fp32 out_w (final) + bf16 scratch
    softmax_k<<<dim3(16 * 1024), blk, 0, stream>>>(out_e, out_w, weights_bf);
    // K4: wc = weights @ enc (via encT^T) -> bf16 (enc_bf slot, enc dead)
    gemm_bt<MODE_WC><<<gG, blk, 0, stream>>>(weights_bf, nullptr, encT_bf, nullptr,
                                             encwc_bf, nullptr);
    // K5: h_tilde = tanh([wc|hidden] @ W_out^T) -> fp32 out_h (scratch dead)
    gemm_bt<MODE_OUT><<<gG, blk, 0, stream>>>(encwc_bf, hidden_bf, wout_bf, nullptr,
                                              nullptr, out_h);
}